// Round 5
// baseline (523.114 us; speedup 1.0000x reference)
//
#include <hip/hip_runtime.h>

typedef unsigned short u16;
typedef __attribute__((ext_vector_type(8))) short bf16x8;
typedef __attribute__((ext_vector_type(4))) float f32x4;
typedef __attribute__((ext_vector_type(4))) u16 u16x4;

#define T_TOK 16384
#define D_DIM 1024
#define NE 8
#define MAXP 33792   // max padded compact rows: 2*T + 8*128

__device__ __forceinline__ u16 f2bf(float f) {
  union { float f; unsigned int u; } c; c.f = f;
  unsigned int u = c.u;
  u += 0x7fffu + ((u >> 16) & 1u);   // round-to-nearest-even
  return (u16)(u >> 16);
}

__device__ __forceinline__ float bf2f(u16 v) {
  union { unsigned int u; float f; } c; c.u = ((unsigned int)v) << 16;
  return c.f;
}

__device__ __forceinline__ float gelu_exact(float u) {
  return 0.5f * u * (1.0f + erff(u * 0.70710678118654752f));
}

__device__ __forceinline__ void gld16(const void* g, void* l) {
  __builtin_amdgcn_global_load_lds(
      (const __attribute__((address_space(1))) unsigned int*)g,
      (__attribute__((address_space(3))) unsigned int*)l, 16, 0, 0);
}

// Stage a 128-row x 64-col bf16 tile (contiguous rows) into linear LDS [128][64].
__device__ __forceinline__ void stage_tile(u16* lds, const char* g0, size_t stride,
                                           int wid, int lane) {
  const char* g = g0 + (size_t)(wid * 8 + (lane >> 3)) * stride + (size_t)((lane & 7) * 16);
  char* l = (char*)lds + wid * 1024;   // wave-uniform LDS base; HW adds lane*16
  #pragma unroll
  for (int c = 0; c < 4; ++c)
    gld16(g + (size_t)(32 * c) * stride, l + c * 4096);
}

// One BK=64 step: 32 MFMA per wave, acc[4][4] (64x64 per wave, 2x2 waves = 128x128)
__device__ __forceinline__ void mma_step(const u16* As, const u16* Bs, f32x4 acc[4][4],
                                         int wm, int wn, int lane) {
  const int r = lane & 15, kq = (lane >> 4) * 8;
  #pragma unroll
  for (int ks = 0; ks < 2; ++ks) {
    const int col = ks * 32 + kq;
    bf16x8 a[4], b[4];
    #pragma unroll
    for (int mf = 0; mf < 4; ++mf)
      a[mf] = *(const bf16x8*)&As[(wm * 64 + mf * 16 + r) * 64 + col];
    #pragma unroll
    for (int nf = 0; nf < 4; ++nf)
      b[nf] = *(const bf16x8*)&Bs[(wn * 64 + nf * 16 + r) * 64 + col];
    #pragma unroll
    for (int mf = 0; mf < 4; ++mf)
      #pragma unroll
      for (int nf = 0; nf < 4; ++nf)
        acc[mf][nf] = __builtin_amdgcn_mfma_f32_16x16x32_bf16(a[mf], b[nf], acc[mf][nf], 0, 0, 0);
  }
}

// ---------------- tiled transpose+convert: in[e][R][C] f32 -> out[e][C][R] bf16 ----------------
__global__ __launch_bounds__(256) void transpose_cvt_kernel(const float* __restrict__ in,
                                                            u16* __restrict__ out,
                                                            int R, int C) {
  __shared__ u16 t[32][36];
  const int e = blockIdx.z;
  const int r0 = blockIdx.x * 32, c0 = blockIdx.y * 32;
  const int tid = threadIdx.x;
  {
    const int r = tid >> 3, cq = (tid & 7) * 4;
    float4 v = *(const float4*)(in + ((size_t)e * R + r0 + r) * C + c0 + cq);
    t[r][cq + 0] = f2bf(v.x); t[r][cq + 1] = f2bf(v.y);
    t[r][cq + 2] = f2bf(v.z); t[r][cq + 3] = f2bf(v.w);
  }
  __syncthreads();
  {
    const int c = tid >> 3, rq = (tid & 7) * 4;
    u16x4 o;
    o.x = t[rq + 0][c]; o.y = t[rq + 1][c]; o.z = t[rq + 2][c]; o.w = t[rq + 3][c];
    *(u16x4*)(out + ((size_t)e * C + c0 + c) * R + r0 + rq) = o;
  }
}

// ---------------- fused gating (double-buffered 2-phase pipeline) ----------------
// 256 threads, 32 tokens/block, BN=256 (full), BK=32. Emits xb (bf16 x), top-2
// indices/gates per token, and per-expert counts (atomic).
__global__ __launch_bounds__(256, 2) void gating_fused_kernel(
    const float* __restrict__ x, const float* __restrict__ wg1,
    const float* __restrict__ bg1, const float* __restrict__ wg2,
    const float* __restrict__ bg2, u16* __restrict__ xb,
    int* __restrict__ top_i, float2* __restrict__ top_g, int* __restrict__ cnt) {
  __shared__ float As[2][32][36];    // transposed x chunk [k][m]
  __shared__ float Bs[2][32 * 256];  // wg1 chunk [k][n], linear for global_load_lds
  const int tid = threadIdx.x;
  const int lane = tid & 63, w = tid >> 6;
  const int tn = tid & 31, tm = tid >> 5;
  const int t0 = blockIdx.x * 32;
  const int srow = tid >> 3, sc4 = (tid & 7) * 4;

  float acc[4][8];
  #pragma unroll
  for (int i = 0; i < 4; ++i)
    #pragma unroll
    for (int j = 0; j < 8; ++j) acc[i][j] = 0.f;

  // ---- prologue: stage k0=0 into buffer 0 ----
  {
    const char* g = (const char*)wg1 + (size_t)(w * 8) * 1024 + lane * 16;
    char* l = (char*)&Bs[0][0] + w * 8192;
    #pragma unroll
    for (int i = 0; i < 8; ++i) gld16(g + i * 1024, l + i * 1024);
  }
  {
    const float* src = x + (size_t)(t0 + srow) * 1024 + sc4;
    float4 v = *(const float4*)src;
    As[0][sc4 + 0][srow] = v.x; As[0][sc4 + 1][srow] = v.y;
    As[0][sc4 + 2][srow] = v.z; As[0][sc4 + 3][srow] = v.w;
    u16x4 o; o.x = f2bf(v.x); o.y = f2bf(v.y); o.z = f2bf(v.z); o.w = f2bf(v.w);
    *(u16x4*)(xb + (size_t)(t0 + srow) * 1024 + sc4) = o;
  }
  __syncthreads();

  int cur = 0;
  for (int k0 = 0; k0 < 1024; k0 += 32) {
    const bool has_next = (k0 + 32) < 1024;
    float4 xv;
    if (has_next) {
      const char* g = (const char*)wg1 + (size_t)(k0 + 32 + w * 8) * 1024 + lane * 16;
      char* l = (char*)&Bs[cur ^ 1][0] + w * 8192;
      #pragma unroll
      for (int i = 0; i < 8; ++i) gld16(g + i * 1024, l + i * 1024);
      xv = *(const float4*)(x + (size_t)(t0 + srow) * 1024 + k0 + 32 + sc4);
    }
    #pragma unroll 4
    for (int kk = 0; kk < 32; ++kk) {
      float4 a4 = *(const float4*)&As[cur][kk][tm * 4];
      float4 b0 = *(const float4*)&Bs[cur][kk * 256 + tn * 4];
      float4 b1 = *(const float4*)&Bs[cur][kk * 256 + 128 + tn * 4];
      float av[4] = {a4.x, a4.y, a4.z, a4.w};
      float bv[8] = {b0.x, b0.y, b0.z, b0.w, b1.x, b1.y, b1.z, b1.w};
      #pragma unroll
      for (int i = 0; i < 4; ++i)
        #pragma unroll
        for (int j = 0; j < 8; ++j) acc[i][j] += av[i] * bv[j];
    }
    if (has_next) {
      As[cur ^ 1][sc4 + 0][srow] = xv.x; As[cur ^ 1][sc4 + 1][srow] = xv.y;
      As[cur ^ 1][sc4 + 2][srow] = xv.z; As[cur ^ 1][sc4 + 3][srow] = xv.w;
      u16x4 o; o.x = f2bf(xv.x); o.y = f2bf(xv.y); o.z = f2bf(xv.z); o.w = f2bf(xv.w);
      *(u16x4*)(xb + (size_t)(t0 + srow) * 1024 + k0 + 32 + sc4) = o;
    }
    __syncthreads();
    cur ^= 1;
  }

  // bias + gelu + GEMM2 partials over this thread's 8 cols
  float bb[8];
  {
    float4 ba = *(const float4*)&bg1[tn * 4];
    float4 bc = *(const float4*)&bg1[128 + tn * 4];
    bb[0] = ba.x; bb[1] = ba.y; bb[2] = ba.z; bb[3] = ba.w;
    bb[4] = bc.x; bb[5] = bc.y; bb[6] = bc.z; bb[7] = bc.w;
  }
  float part[4][8];
  #pragma unroll
  for (int i = 0; i < 4; ++i)
    #pragma unroll
    for (int e = 0; e < 8; ++e) part[i][e] = 0.f;
  #pragma unroll
  for (int j = 0; j < 8; ++j) {
    const int col = (j < 4) ? (tn * 4 + j) : (128 + tn * 4 + (j - 4));
    float4 wa = *(const float4*)&wg2[col * 8];
    float4 wb = *(const float4*)&wg2[col * 8 + 4];
    float we[8] = {wa.x, wa.y, wa.z, wa.w, wb.x, wb.y, wb.z, wb.w};
    #pragma unroll
    for (int i = 0; i < 4; ++i) {
      float h = gelu_exact(acc[i][j] + bb[j]);
      #pragma unroll
      for (int e = 0; e < 8; ++e) part[i][e] += h * we[e];
    }
  }
  #pragma unroll
  for (int mask = 1; mask < 32; mask <<= 1)
    #pragma unroll
    for (int i = 0; i < 4; ++i)
      #pragma unroll
      for (int e = 0; e < 8; ++e) part[i][e] += __shfl_xor(part[i][e], mask);

  // softmax + top2: lane tn=i handles token tm*4+i
  if (tn < 4) {
    float lg[8];
    #pragma unroll
    for (int i = 0; i < 4; ++i)
      if (tn == i) {
        #pragma unroll
        for (int e = 0; e < 8; ++e) lg[e] = part[i][e];
      }
    #pragma unroll
    for (int e = 0; e < 8; ++e) lg[e] += bg2[e];
    float m = lg[0];
    #pragma unroll
    for (int e = 1; e < 8; ++e) m = fmaxf(m, lg[e]);
    float ex[8], s = 0.f;
    #pragma unroll
    for (int e = 0; e < 8; ++e) { ex[e] = expf(lg[e] - m); s += ex[e]; }
    int i1 = 0;
    #pragma unroll
    for (int e = 1; e < 8; ++e) if (lg[e] > lg[i1]) i1 = e;   // strict >: lowest idx on tie
    int i2 = (i1 == 0) ? 1 : 0;
    #pragma unroll
    for (int e = 0; e < 8; ++e) if (e != i1 && lg[e] > lg[i2]) i2 = e;
    float inv = 1.f / s;
    const int t = t0 + tm * 4 + tn;
    top_i[t] = i1 | (i2 << 8);
    top_g[t] = make_float2(ex[i1] * inv, ex[i2] * inv);
    atomicAdd(&cnt[i1], 1);
    atomicAdd(&cnt[i2], 1);
  }
}

// ---------------- scan: padded exclusive offsets over 8 counts ----------------
__global__ void scan_kernel(const int* __restrict__ cnt, int* __restrict__ offs) {
  if (threadIdx.x == 0) {
    int o = 0;
    #pragma unroll
    for (int e = 0; e < NE; ++e) { offs[e] = o; o += (cnt[e] + 127) & ~127; }
  }
}

// ---------------- fill: scatter tokens into per-expert compact lists ----------------
__global__ __launch_bounds__(256) void fill_kernel(
    const int* __restrict__ top_i, const int* __restrict__ offs,
    int* __restrict__ cnt2, int* __restrict__ tok_list,
    int* __restrict__ pos1, int* __restrict__ pos2) {
  const int t = blockIdx.x * 256 + threadIdx.x;
  const int ti = top_i[t];
  const int i1 = ti & 255, i2 = ti >> 8;
  const int p1 = offs[i1] + atomicAdd(&cnt2[i1], 1);
  const int p2 = offs[i2] + atomicAdd(&cnt2[i2], 1);
  tok_list[p1] = t; tok_list[p2] = t;
  pos1[t] = p1; pos2[t] = p2;
}

// ---------------- pass A (compact): h[p][h] = gelu(x[tok[p]] @ W1e + b1e), bf16 ----------------
__global__ __launch_bounds__(256) void expert_h_kernel(
    const u16* __restrict__ xb, const u16* __restrict__ w1t,
    const float* __restrict__ b1, const int* __restrict__ tok_list,
    const int* __restrict__ cnt, const int* __restrict__ offs,
    u16* __restrict__ h_c) {
  __shared__ u16 As[128 * 64];
  __shared__ u16 Bs[128 * 64];
  __shared__ float b1_s[128];
  const int e = blockIdx.z;
  const int nblk = (cnt[e] + 127) >> 7;
  if ((int)blockIdx.x >= nblk) return;
  const int tid = threadIdx.x, lane = tid & 63, wid = tid >> 6;
  const int base = offs[e] + blockIdx.x * 128;
  const int n0 = blockIdx.y * 128;
  const int wm = wid >> 1, wn = wid & 1;

  if (tid < 128) b1_s[tid] = b1[e * 256 + n0 + tid];

  // token ids for this wave's staged rows (hoisted out of the K loop)
  int tk[4];
  {
    const int r0 = wid * 8 + (lane >> 3);
    #pragma unroll
    for (int c = 0; c < 4; ++c) tk[c] = tok_list[base + r0 + 32 * c];
  }

  f32x4 acc[4][4];
  #pragma unroll
  for (int i = 0; i < 4; ++i)
    #pragma unroll
    for (int j = 0; j < 4; ++j) acc[i][j] = (f32x4){0.f, 0.f, 0.f, 0.f};

  const char* Bb = (const char*)w1t + ((size_t)e * 256 + n0) * 2048;
  const int cb = (lane & 7) * 16;
  for (int kt = 0; kt < 16; ++kt) {
    __syncthreads();
    {   // gather-stage A: per-lane global row = tok_list row
      char* l = (char*)As + wid * 1024;
      #pragma unroll
      for (int c = 0; c < 4; ++c)
        gld16((const char*)xb + (size_t)tk[c] * 2048 + kt * 128 + cb, l + c * 4096);
    }
    stage_tile(Bs, Bb + kt * 128, 2048, wid, lane);
    __syncthreads();
    mma_step(As, Bs, acc, wm, wn, lane);
  }

  #pragma unroll
  for (int mf = 0; mf < 4; ++mf)
    #pragma unroll
    for (int rr = 0; rr < 4; ++rr) {
      const int lt = wm * 64 + mf * 16 + ((lane >> 4) << 2) + rr;
      #pragma unroll
      for (int nf = 0; nf < 4; ++nf) {
        const int ln = wn * 64 + nf * 16 + (lane & 15);
        float u = acc[mf][nf][rr] + b1_s[ln];
        h_c[(size_t)(base + lt) * 256 + n0 + ln] = f2bf(gelu_exact(u));
      }
    }
}

// ---------------- pass B (compact): o[p][d] = h[p] @ W2e + b2e, bf16 ----------------
__global__ __launch_bounds__(256) void moe_out_kernel(
    const u16* __restrict__ h_c, const u16* __restrict__ w2t,
    const float* __restrict__ b2, const int* __restrict__ cnt,
    const int* __restrict__ offs, u16* __restrict__ o_c) {
  __shared__ u16 As[128 * 64];
  __shared__ u16 Bs[128 * 64];
  __shared__ float b2_s[128];
  const int e = blockIdx.z;
  const int nblk = (cnt[e] + 127) >> 7;
  if ((int)blockIdx.x >= nblk) return;
  const int tid = threadIdx.x, lane = tid & 63, wid = tid >> 6;
  const int base = offs[e] + blockIdx.x * 128;
  const int n0 = blockIdx.y * 128;
  const int wm = wid >> 1, wn = wid & 1;

  if (tid < 128) b2_s[tid] = b2[(size_t)e * 1024 + n0 + tid];

  f32x4 acc[4][4];
  #pragma unroll
  for (int i = 0; i < 4; ++i)
    #pragma unroll
    for (int j = 0; j < 4; ++j) acc[i][j] = (f32x4){0.f, 0.f, 0.f, 0.f};

  const char* Ab = (const char*)h_c + (size_t)base * 512;
  const char* Bb = (const char*)w2t + ((size_t)e * D_DIM + n0) * 512;
  #pragma unroll 1
  for (int kt = 0; kt < 4; ++kt) {
    __syncthreads();
    stage_tile(As, Ab + kt * 128, 512, wid, lane);
    stage_tile(Bs, Bb + kt * 128, 512, wid, lane);
    __syncthreads();
    mma_step(As, Bs, acc, wm, wn, lane);
  }

  #pragma unroll
  for (int mf = 0; mf < 4; ++mf)
    #pragma unroll
    for (int rr = 0; rr < 4; ++rr) {
      const int lt = wm * 64 + mf * 16 + ((lane >> 4) << 2) + rr;
      #pragma unroll
      for (int nf = 0; nf < 4; ++nf) {
        const int ln = wn * 64 + nf * 16 + (lane & 15);
        o_c[(size_t)(base + lt) * 1024 + n0 + ln] = f2bf(acc[mf][nf][rr] + b2_s[ln]);
      }
    }
}

// ---------------- gather: y[t] = g1*o[p1] + g2*o[p2] ----------------
__global__ __launch_bounds__(256) void gather_kernel(
    const u16* __restrict__ o_c, const int* __restrict__ pos1,
    const int* __restrict__ pos2, const float2* __restrict__ top_g,
    float* __restrict__ y) {
  const int t = blockIdx.x;
  const int p1 = pos1[t], p2 = pos2[t];
  const float2 g = top_g[t];
  const int c = threadIdx.x * 4;
  u16x4 a = *(const u16x4*)&o_c[(size_t)p1 * 1024 + c];
  u16x4 b = *(const u16x4*)&o_c[(size_t)p2 * 1024 + c];
  float4 o;
  o.x = g.x * bf2f(a.x) + g.y * bf2f(b.x);
  o.y = g.x * bf2f(a.y) + g.y * bf2f(b.y);
  o.z = g.x * bf2f(a.z) + g.y * bf2f(b.z);
  o.w = g.x * bf2f(a.w) + g.y * bf2f(b.w);
  *(float4*)&y[(size_t)t * 1024 + c] = o;
}

extern "C" void kernel_launch(void* const* d_in, const int* in_sizes, int n_in,
                              void* d_out, int out_size, void* d_ws, size_t ws_size,
                              hipStream_t stream) {
  (void)in_sizes; (void)n_in; (void)out_size; (void)ws_size;
  const float* x   = (const float*)d_in[0];
  const float* wg1 = (const float*)d_in[1];
  const float* bg1 = (const float*)d_in[2];
  const float* wg2 = (const float*)d_in[3];
  const float* bg2 = (const float*)d_in[4];
  const float* w1  = (const float*)d_in[5];
  const float* b1  = (const float*)d_in[6];
  const float* w2  = (const float*)d_in[7];
  const float* b2  = (const float*)d_in[8];
  float* y = (float*)d_out;

  char* ws = (char*)d_ws;
  u16* xb   = (u16*)(ws);                 // 33,554,432 B
  u16* w1t  = (u16*)(ws + 33554432);      //  4,194,304 B
  u16* w2t  = (u16*)(ws + 37748736);      //  4,194,304 B
  char* M   = ws + 41943040;              // metadata block
  int*    cnt      = (int*)(M);                 // 32 B
  int*    cnt2     = (int*)(M + 64);            // 32 B
  int*    offs     = (int*)(M + 128);           // 32 B
  int*    tok_list = (int*)(M + 256);           // 135,168 B -> ends M+135,424
  int*    top_i    = (int*)(M + 135424);        // 65,536 B
  float2* top_g    = (float2*)(M + 200960);     // 131,072 B
  int*    pos1     = (int*)(M + 332032);        // 65,536 B
  int*    pos2     = (int*)(M + 397568);        // 65,536 B -> ends M+463,104
  u16* h_c = (u16*)(ws + 42467328);       // MAXP*256*2 = 17,301,504 B
  u16* o_c = (u16*)(ws + 59768832);       // MAXP*1024*2 = 69,206,016 B (total ~123 MiB)

  // zero cnt/cnt2/offs/tok_list (pad slots -> token 0)
  hipMemsetAsync(M, 0, 135424, stream);
  transpose_cvt_kernel<<<dim3(32, 8, 8), 256, 0, stream>>>(w1, w1t, 1024, 256);
  transpose_cvt_kernel<<<dim3(8, 32, 8), 256, 0, stream>>>(w2, w2t, 256, 1024);
  gating_fused_kernel<<<512, 256, 0, stream>>>(x, wg1, bg1, wg2, bg2, xb, top_i, top_g, cnt);
  scan_kernel<<<1, 1, 0, stream>>>(cnt, offs);
  fill_kernel<<<64, 256, 0, stream>>>(top_i, offs, cnt2, tok_list, pos1, pos2);
  expert_h_kernel<<<dim3(128, 2, 8), 256, 0, stream>>>(xb, w1t, b1, tok_list, cnt, offs, h_c);
  moe_out_kernel <<<dim3(128, 8, 8), 256, 0, stream>>>(h_c, w2t, b2, cnt, offs, o_c);
  gather_kernel  <<<16384, 256, 0, stream>>>(o_c, pos1, pos2, top_g, y);
}

// Round 6
// 261.073 us; speedup vs baseline: 2.0037x; 2.0037x over previous
//
#include <hip/hip_runtime.h>

typedef unsigned short u16;
typedef __attribute__((ext_vector_type(8))) short bf16x8;
typedef __attribute__((ext_vector_type(4))) float f32x4;
typedef __attribute__((ext_vector_type(4))) u16 u16x4;

#define T_TOK 16384
#define D_DIM 1024
#define NE 8
#define MAXP 33792   // max padded compact rows: 2*T + 8*128

__device__ __forceinline__ u16 f2bf(float f) {
  union { float f; unsigned int u; } c; c.f = f;
  unsigned int u = c.u;
  u += 0x7fffu + ((u >> 16) & 1u);   // round-to-nearest-even
  return (u16)(u >> 16);
}

__device__ __forceinline__ float bf2f(u16 v) {
  union { unsigned int u; float f; } c; c.u = ((unsigned int)v) << 16;
  return c.f;
}

__device__ __forceinline__ float gelu_exact(float u) {
  return 0.5f * u * (1.0f + erff(u * 0.70710678118654752f));
}

__device__ __forceinline__ void gld16(const void* g, void* l) {
  __builtin_amdgcn_global_load_lds(
      (const __attribute__((address_space(1))) unsigned int*)g,
      (__attribute__((address_space(3))) unsigned int*)l, 16, 0, 0);
}

// Stage a 128-row x 64-col bf16 tile (contiguous rows) into linear LDS [128][64].
__device__ __forceinline__ void stage_tile(u16* lds, const char* g0, size_t stride,
                                           int wid, int lane) {
  const char* g = g0 + (size_t)(wid * 8 + (lane >> 3)) * stride + (size_t)((lane & 7) * 16);
  char* l = (char*)lds + wid * 1024;   // wave-uniform LDS base; HW adds lane*16
  #pragma unroll
  for (int c = 0; c < 4; ++c)
    gld16(g + (size_t)(32 * c) * stride, l + c * 4096);
}

// One BK=64 step: 32 MFMA per wave, acc[4][4] (64x64 per wave, 2x2 waves = 128x128)
__device__ __forceinline__ void mma_step(const u16* As, const u16* Bs, f32x4 acc[4][4],
                                         int wm, int wn, int lane) {
  const int r = lane & 15, kq = (lane >> 4) * 8;
  #pragma unroll
  for (int ks = 0; ks < 2; ++ks) {
    const int col = ks * 32 + kq;
    bf16x8 a[4], b[4];
    #pragma unroll
    for (int mf = 0; mf < 4; ++mf)
      a[mf] = *(const bf16x8*)&As[(wm * 64 + mf * 16 + r) * 64 + col];
    #pragma unroll
    for (int nf = 0; nf < 4; ++nf)
      b[nf] = *(const bf16x8*)&Bs[(wn * 64 + nf * 16 + r) * 64 + col];
    #pragma unroll
    for (int mf = 0; mf < 4; ++mf)
      #pragma unroll
      for (int nf = 0; nf < 4; ++nf)
        acc[mf][nf] = __builtin_amdgcn_mfma_f32_16x16x32_bf16(a[mf], b[nf], acc[mf][nf], 0, 0, 0);
  }
}

// ---------------- tiled transpose+convert: in[e][R][C] f32 -> out[e][C][R] bf16 ----------------
__global__ __launch_bounds__(256) void transpose_cvt_kernel(const float* __restrict__ in,
                                                            u16* __restrict__ out,
                                                            int R, int C) {
  __shared__ u16 t[32][36];
  const int e = blockIdx.z;
  const int r0 = blockIdx.x * 32, c0 = blockIdx.y * 32;
  const int tid = threadIdx.x;
  {
    const int r = tid >> 3, cq = (tid & 7) * 4;
    float4 v = *(const float4*)(in + ((size_t)e * R + r0 + r) * C + c0 + cq);
    t[r][cq + 0] = f2bf(v.x); t[r][cq + 1] = f2bf(v.y);
    t[r][cq + 2] = f2bf(v.z); t[r][cq + 3] = f2bf(v.w);
  }
  __syncthreads();
  {
    const int c = tid >> 3, rq = (tid & 7) * 4;
    u16x4 o;
    o.x = t[rq + 0][c]; o.y = t[rq + 1][c]; o.z = t[rq + 2][c]; o.w = t[rq + 3][c];
    *(u16x4*)(out + ((size_t)e * C + c0 + c) * R + r0 + rq) = o;
  }
}

// ---------------- fused gating (double-buffered 2-phase pipeline, NO atomics) ----------------
// 256 threads, 32 tokens/block, BN=256 (full), BK=32. Emits xb (bf16 x) and top-2
// indices/gates per token.
__global__ __launch_bounds__(256, 2) void gating_fused_kernel(
    const float* __restrict__ x, const float* __restrict__ wg1,
    const float* __restrict__ bg1, const float* __restrict__ wg2,
    const float* __restrict__ bg2, u16* __restrict__ xb,
    int* __restrict__ top_i, float2* __restrict__ top_g) {
  __shared__ float As[2][32][36];    // transposed x chunk [k][m]
  __shared__ float Bs[2][32 * 256];  // wg1 chunk [k][n], linear for global_load_lds
  const int tid = threadIdx.x;
  const int lane = tid & 63, w = tid >> 6;
  const int tn = tid & 31, tm = tid >> 5;
  const int t0 = blockIdx.x * 32;
  const int srow = tid >> 3, sc4 = (tid & 7) * 4;

  float acc[4][8];
  #pragma unroll
  for (int i = 0; i < 4; ++i)
    #pragma unroll
    for (int j = 0; j < 8; ++j) acc[i][j] = 0.f;

  // ---- prologue: stage k0=0 into buffer 0 ----
  {
    const char* g = (const char*)wg1 + (size_t)(w * 8) * 1024 + lane * 16;
    char* l = (char*)&Bs[0][0] + w * 8192;
    #pragma unroll
    for (int i = 0; i < 8; ++i) gld16(g + i * 1024, l + i * 1024);
  }
  {
    const float* src = x + (size_t)(t0 + srow) * 1024 + sc4;
    float4 v = *(const float4*)src;
    As[0][sc4 + 0][srow] = v.x; As[0][sc4 + 1][srow] = v.y;
    As[0][sc4 + 2][srow] = v.z; As[0][sc4 + 3][srow] = v.w;
    u16x4 o; o.x = f2bf(v.x); o.y = f2bf(v.y); o.z = f2bf(v.z); o.w = f2bf(v.w);
    *(u16x4*)(xb + (size_t)(t0 + srow) * 1024 + sc4) = o;
  }
  __syncthreads();

  int cur = 0;
  for (int k0 = 0; k0 < 1024; k0 += 32) {
    const bool has_next = (k0 + 32) < 1024;
    float4 xv;
    if (has_next) {
      const char* g = (const char*)wg1 + (size_t)(k0 + 32 + w * 8) * 1024 + lane * 16;
      char* l = (char*)&Bs[cur ^ 1][0] + w * 8192;
      #pragma unroll
      for (int i = 0; i < 8; ++i) gld16(g + i * 1024, l + i * 1024);
      xv = *(const float4*)(x + (size_t)(t0 + srow) * 1024 + k0 + 32 + sc4);
    }
    #pragma unroll 4
    for (int kk = 0; kk < 32; ++kk) {
      float4 a4 = *(const float4*)&As[cur][kk][tm * 4];
      float4 b0 = *(const float4*)&Bs[cur][kk * 256 + tn * 4];
      float4 b1 = *(const float4*)&Bs[cur][kk * 256 + 128 + tn * 4];
      float av[4] = {a4.x, a4.y, a4.z, a4.w};
      float bv[8] = {b0.x, b0.y, b0.z, b0.w, b1.x, b1.y, b1.z, b1.w};
      #pragma unroll
      for (int i = 0; i < 4; ++i)
        #pragma unroll
        for (int j = 0; j < 8; ++j) acc[i][j] += av[i] * bv[j];
    }
    if (has_next) {
      As[cur ^ 1][sc4 + 0][srow] = xv.x; As[cur ^ 1][sc4 + 1][srow] = xv.y;
      As[cur ^ 1][sc4 + 2][srow] = xv.z; As[cur ^ 1][sc4 + 3][srow] = xv.w;
      u16x4 o; o.x = f2bf(xv.x); o.y = f2bf(xv.y); o.z = f2bf(xv.z); o.w = f2bf(xv.w);
      *(u16x4*)(xb + (size_t)(t0 + srow) * 1024 + k0 + 32 + sc4) = o;
    }
    __syncthreads();
    cur ^= 1;
  }

  // bias + gelu + GEMM2 partials over this thread's 8 cols
  float bb[8];
  {
    float4 ba = *(const float4*)&bg1[tn * 4];
    float4 bc = *(const float4*)&bg1[128 + tn * 4];
    bb[0] = ba.x; bb[1] = ba.y; bb[2] = ba.z; bb[3] = ba.w;
    bb[4] = bc.x; bb[5] = bc.y; bb[6] = bc.z; bb[7] = bc.w;
  }
  float part[4][8];
  #pragma unroll
  for (int i = 0; i < 4; ++i)
    #pragma unroll
    for (int e = 0; e < 8; ++e) part[i][e] = 0.f;
  #pragma unroll
  for (int j = 0; j < 8; ++j) {
    const int col = (j < 4) ? (tn * 4 + j) : (128 + tn * 4 + (j - 4));
    float4 wa = *(const float4*)&wg2[col * 8];
    float4 wb = *(const float4*)&wg2[col * 8 + 4];
    float we[8] = {wa.x, wa.y, wa.z, wa.w, wb.x, wb.y, wb.z, wb.w};
    #pragma unroll
    for (int i = 0; i < 4; ++i) {
      float h = gelu_exact(acc[i][j] + bb[j]);
      #pragma unroll
      for (int e = 0; e < 8; ++e) part[i][e] += h * we[e];
    }
  }
  #pragma unroll
  for (int mask = 1; mask < 32; mask <<= 1)
    #pragma unroll
    for (int i = 0; i < 4; ++i)
      #pragma unroll
      for (int e = 0; e < 8; ++e) part[i][e] += __shfl_xor(part[i][e], mask);

  // softmax + top2: lane tn=i handles token tm*4+i
  if (tn < 4) {
    float lg[8];
    #pragma unroll
    for (int i = 0; i < 4; ++i)
      if (tn == i) {
        #pragma unroll
        for (int e = 0; e < 8; ++e) lg[e] = part[i][e];
      }
    #pragma unroll
    for (int e = 0; e < 8; ++e) lg[e] += bg2[e];
    float m = lg[0];
    #pragma unroll
    for (int e = 1; e < 8; ++e) m = fmaxf(m, lg[e]);
    float ex[8], s = 0.f;
    #pragma unroll
    for (int e = 0; e < 8; ++e) { ex[e] = expf(lg[e] - m); s += ex[e]; }
    int i1 = 0;
    #pragma unroll
    for (int e = 1; e < 8; ++e) if (lg[e] > lg[i1]) i1 = e;   // strict >: lowest idx on tie
    int i2 = (i1 == 0) ? 1 : 0;
    #pragma unroll
    for (int e = 0; e < 8; ++e) if (e != i1 && lg[e] > lg[i2]) i2 = e;
    float inv = 1.f / s;
    const int t = t0 + tm * 4 + tn;
    top_i[t] = i1 | (i2 << 8);
    top_g[t] = make_float2(ex[i1] * inv, ex[i2] * inv);
  }
}

// ---------------- hist: per-256-token-chunk expert histogram (LDS atomics only) ----------------
__global__ __launch_bounds__(256) void hist_kernel(const int* __restrict__ top_i,
                                                   int* __restrict__ hist) {
  __shared__ int h[NE];
  const int tid = threadIdx.x;
  if (tid < NE) h[tid] = 0;
  __syncthreads();
  const int ti = top_i[blockIdx.x * 256 + tid];
  atomicAdd(&h[ti & 255], 1);
  atomicAdd(&h[ti >> 8], 1);
  __syncthreads();
  if (tid < NE) hist[blockIdx.x * NE + tid] = h[tid];
}

// ---------------- scan: totals, padded offsets, per-chunk bases (single block) ----------------
__global__ __launch_bounds__(64) void scan_kernel(const int* __restrict__ hist,
                                                  int* __restrict__ cnt,
                                                  int* __restrict__ offs,
                                                  int* __restrict__ cbase) {
  __shared__ int tot[NE], off_s[NE];
  const int tid = threadIdx.x;
  if (tid < NE) {
    int s = 0;
    for (int c = 0; c < 64; ++c) s += hist[c * NE + tid];
    tot[tid] = s; cnt[tid] = s;
  }
  __syncthreads();
  if (tid == 0) {
    int o = 0;
    #pragma unroll
    for (int e = 0; e < NE; ++e) { off_s[e] = o; o += (tot[e] + 127) & ~127; }
  }
  __syncthreads();
  if (tid < NE) {
    offs[tid] = off_s[tid];
    int r = off_s[tid];
    for (int c = 0; c < 64; ++c) { cbase[c * NE + tid] = r; r += hist[c * NE + tid]; }
  }
}

// ---------------- fill: scatter tokens into per-expert compact lists (LDS atomics) ----------------
__global__ __launch_bounds__(256) void fill_kernel(
    const int* __restrict__ top_i, const int* __restrict__ cbase,
    int* __restrict__ tok_list, int* __restrict__ pos1, int* __restrict__ pos2) {
  __shared__ int lcnt[NE];
  const int tid = threadIdx.x;
  if (tid < NE) lcnt[tid] = 0;
  __syncthreads();
  const int t = blockIdx.x * 256 + tid;
  const int ti = top_i[t];
  const int i1 = ti & 255, i2 = ti >> 8;
  const int r1 = atomicAdd(&lcnt[i1], 1);
  const int r2 = atomicAdd(&lcnt[i2], 1);
  const int p1 = cbase[blockIdx.x * NE + i1] + r1;
  const int p2 = cbase[blockIdx.x * NE + i2] + r2;
  tok_list[p1] = t; tok_list[p2] = t;
  pos1[t] = p1; pos2[t] = p2;
}

// ---------------- pass A (compact): h[p][h] = gelu(x[tok[p]] @ W1e + b1e), bf16 ----------------
__global__ __launch_bounds__(256) void expert_h_kernel(
    const u16* __restrict__ xb, const u16* __restrict__ w1t,
    const float* __restrict__ b1, const int* __restrict__ tok_list,
    const int* __restrict__ cnt, const int* __restrict__ offs,
    u16* __restrict__ h_c) {
  __shared__ u16 As[128 * 64];
  __shared__ u16 Bs[128 * 64];
  __shared__ float b1_s[128];
  const int e = blockIdx.z;
  const int nblk = (cnt[e] + 127) >> 7;
  if ((int)blockIdx.x >= nblk) return;
  const int tid = threadIdx.x, lane = tid & 63, wid = tid >> 6;
  const int base = offs[e] + blockIdx.x * 128;
  const int n0 = blockIdx.y * 128;
  const int wm = wid >> 1, wn = wid & 1;

  if (tid < 128) b1_s[tid] = b1[e * 256 + n0 + tid];

  // token ids for this wave's staged rows (hoisted out of the K loop)
  int tk[4];
  {
    const int r0 = wid * 8 + (lane >> 3);
    #pragma unroll
    for (int c = 0; c < 4; ++c) tk[c] = tok_list[base + r0 + 32 * c];
  }

  f32x4 acc[4][4];
  #pragma unroll
  for (int i = 0; i < 4; ++i)
    #pragma unroll
    for (int j = 0; j < 4; ++j) acc[i][j] = (f32x4){0.f, 0.f, 0.f, 0.f};

  const char* Bb = (const char*)w1t + ((size_t)e * 256 + n0) * 2048;
  const int cb = (lane & 7) * 16;
  for (int kt = 0; kt < 16; ++kt) {
    __syncthreads();
    {   // gather-stage A: per-lane global row = tok_list row
      char* l = (char*)As + wid * 1024;
      #pragma unroll
      for (int c = 0; c < 4; ++c)
        gld16((const char*)xb + (size_t)tk[c] * 2048 + kt * 128 + cb, l + c * 4096);
    }
    stage_tile(Bs, Bb + kt * 128, 2048, wid, lane);
    __syncthreads();
    mma_step(As, Bs, acc, wm, wn, lane);
  }

  #pragma unroll
  for (int mf = 0; mf < 4; ++mf)
    #pragma unroll
    for (int rr = 0; rr < 4; ++rr) {
      const int lt = wm * 64 + mf * 16 + ((lane >> 4) << 2) + rr;
      #pragma unroll
      for (int nf = 0; nf < 4; ++nf) {
        const int ln = wn * 64 + nf * 16 + (lane & 15);
        float u = acc[mf][nf][rr] + b1_s[ln];
        h_c[(size_t)(base + lt) * 256 + n0 + ln] = f2bf(gelu_exact(u));
      }
    }
}

// ---------------- pass B (compact): o[p][d] = h[p] @ W2e + b2e, bf16 ----------------
__global__ __launch_bounds__(256) void moe_out_kernel(
    const u16* __restrict__ h_c, const u16* __restrict__ w2t,
    const float* __restrict__ b2, const int* __restrict__ cnt,
    const int* __restrict__ offs, u16* __restrict__ o_c) {
  __shared__ u16 As[128 * 64];
  __shared__ u16 Bs[128 * 64];
  __shared__ float b2_s[128];
  const int e = blockIdx.z;
  const int nblk = (cnt[e] + 127) >> 7;
  if ((int)blockIdx.x >= nblk) return;
  const int tid = threadIdx.x, lane = tid & 63, wid = tid >> 6;
  const int base = offs[e] + blockIdx.x * 128;
  const int n0 = blockIdx.y * 128;
  const int wm = wid >> 1, wn = wid & 1;

  if (tid < 128) b2_s[tid] = b2[(size_t)e * 1024 + n0 + tid];

  f32x4 acc[4][4];
  #pragma unroll
  for (int i = 0; i < 4; ++i)
    #pragma unroll
    for (int j = 0; j < 4; ++j) acc[i][j] = (f32x4){0.f, 0.f, 0.f, 0.f};

  const char* Ab = (const char*)h_c + (size_t)base * 512;
  const char* Bb = (const char*)w2t + ((size_t)e * D_DIM + n0) * 512;
  #pragma unroll 1
  for (int kt = 0; kt < 4; ++kt) {
    __syncthreads();
    stage_tile(As, Ab + kt * 128, 512, wid, lane);
    stage_tile(Bs, Bb + kt * 128, 512, wid, lane);
    __syncthreads();
    mma_step(As, Bs, acc, wm, wn, lane);
  }

  #pragma unroll
  for (int mf = 0; mf < 4; ++mf)
    #pragma unroll
    for (int rr = 0; rr < 4; ++rr) {
      const int lt = wm * 64 + mf * 16 + ((lane >> 4) << 2) + rr;
      #pragma unroll
      for (int nf = 0; nf < 4; ++nf) {
        const int ln = wn * 64 + nf * 16 + (lane & 15);
        o_c[(size_t)(base + lt) * 1024 + n0 + ln] = f2bf(acc[mf][nf][rr] + b2_s[ln]);
      }
    }
}

// ---------------- gather: y[t] = g1*o[p1] + g2*o[p2] ----------------
__global__ __launch_bounds__(256) void gather_kernel(
    const u16* __restrict__ o_c, const int* __restrict__ pos1,
    const int* __restrict__ pos2, const float2* __restrict__ top_g,
    float* __restrict__ y) {
  const int t = blockIdx.x;
  const int p1 = pos1[t], p2 = pos2[t];
  const float2 g = top_g[t];
  const int c = threadIdx.x * 4;
  u16x4 a = *(const u16x4*)&o_c[(size_t)p1 * 1024 + c];
  u16x4 b = *(const u16x4*)&o_c[(size_t)p2 * 1024 + c];
  float4 o;
  o.x = g.x * bf2f(a.x) + g.y * bf2f(b.x);
  o.y = g.x * bf2f(a.y) + g.y * bf2f(b.y);
  o.z = g.x * bf2f(a.z) + g.y * bf2f(b.z);
  o.w = g.x * bf2f(a.w) + g.y * bf2f(b.w);
  *(float4*)&y[(size_t)t * 1024 + c] = o;
}

extern "C" void kernel_launch(void* const* d_in, const int* in_sizes, int n_in,
                              void* d_out, int out_size, void* d_ws, size_t ws_size,
                              hipStream_t stream) {
  (void)in_sizes; (void)n_in; (void)out_size; (void)ws_size;
  const float* x   = (const float*)d_in[0];
  const float* wg1 = (const float*)d_in[1];
  const float* bg1 = (const float*)d_in[2];
  const float* wg2 = (const float*)d_in[3];
  const float* bg2 = (const float*)d_in[4];
  const float* w1  = (const float*)d_in[5];
  const float* b1  = (const float*)d_in[6];
  const float* w2  = (const float*)d_in[7];
  const float* b2  = (const float*)d_in[8];
  float* y = (float*)d_out;

  char* ws = (char*)d_ws;
  u16* xb   = (u16*)(ws);                 // 33,554,432 B
  u16* w1t  = (u16*)(ws + 33554432);      //  4,194,304 B
  u16* w2t  = (u16*)(ws + 37748736);      //  4,194,304 B
  char* M   = ws + 41943040;              // metadata block
  int*    cnt      = (int*)(M);                 // 32 B
  int*    offs     = (int*)(M + 64);            // 32 B
  int*    hist     = (int*)(M + 128);           // 2,048 B
  int*    cbase    = (int*)(M + 2304);          // 2,048 B
  int*    tok_list = (int*)(M + 4608);          // 135,168 B -> ends M+139,776
  int*    top_i    = (int*)(M + 139776);        // 65,536 B
  float2* top_g    = (float2*)(M + 205312);     // 131,072 B
  int*    pos1     = (int*)(M + 336384);        // 65,536 B
  int*    pos2     = (int*)(M + 401920);        // 65,536 B -> ends M+467,456
  u16* h_c = (u16*)(ws + 42467328);       // MAXP*256*2 = 17,301,504 B
  u16* o_c = (u16*)(ws + 59768832);       // MAXP*1024*2 = 69,206,016 B (total ~123 MiB)

  // zero tok_list (pad slots -> token 0); everything else fully overwritten each call
  hipMemsetAsync(tok_list, 0, 135168, stream);
  transpose_cvt_kernel<<<dim3(32, 8, 8), 256, 0, stream>>>(w1, w1t, 1024, 256);
  transpose_cvt_kernel<<<dim3(8, 32, 8), 256, 0, stream>>>(w2, w2t, 256, 1024);
  gating_fused_kernel<<<512, 256, 0, stream>>>(x, wg1, bg1, wg2, bg2, xb, top_i, top_g);
  hist_kernel<<<64, 256, 0, stream>>>(top_i, hist);
  scan_kernel<<<1, 64, 0, stream>>>(hist, cnt, offs, cbase);
  fill_kernel<<<64, 256, 0, stream>>>(top_i, cbase, tok_list, pos1, pos2);
  expert_h_kernel<<<dim3(128, 2, 8), 256, 0, stream>>>(xb, w1t, b1, tok_list, cnt, offs, h_c);
  moe_out_kernel <<<dim3(128, 8, 8), 256, 0, stream>>>(h_c, w2t, b2, cnt, offs, o_c);
  gather_kernel  <<<16384, 256, 0, stream>>>(o_c, pos1, pos2, top_g, y);
}